// Round 14
// baseline (184.506 us; speedup 1.0000x reference)
//
#include <hip/hip_runtime.h>
#include <math.h>

#define NN   2048
#define INF_ 256
#define OUTF 256
#define EF   64
#define ALPHA 0.2f
#define NEG_INF -9000000000000000.0f

typedef unsigned short ushortT;
typedef __attribute__((ext_vector_type(8))) short    short8v;
typedef __attribute__((ext_vector_type(4))) short    short4v;
typedef __attribute__((ext_vector_type(8))) unsigned short u16x8;
typedef __attribute__((ext_vector_type(4))) float    f32x4;
typedef __attribute__((ext_vector_type(4))) float    fv4;   // clang vector: NT-load legal
typedef __attribute__((ext_vector_type(4))) int      iv4;

__device__ __forceinline__ ushortT f2b(float f) {      // RNE; inputs are finite
    unsigned b = *(unsigned*)&f;
    unsigned r = (b + 0x7FFFu + ((b >> 16) & 1u)) >> 16;
    return (ushortT)r;
}
// quad_perm DPP lane-xor add (VALU pipe, no LDS)
__device__ __forceinline__ float dpp_add_xor1(float x) {
    int xi = *(int*)&x;
    int r = __builtin_amdgcn_mov_dpp(xi, 0xB1, 0xF, 0xF, true);  // [1,0,3,2]
    float rf = *(float*)&r;
    return x + rf;
}
__device__ __forceinline__ float dpp_add_xor2(float x) {
    int xi = *(int*)&x;
    int r = __builtin_amdgcn_mov_dpp(xi, 0x4E, 0xF, 0xF, true);  // [2,3,0,1]
    float rf = *(float*)&r;
    return x + rf;
}
__device__ __forceinline__ fv4 ntload4(const float* p) {
    return __builtin_nontemporal_load((const fv4*)p);
}

// ---------------- prep_w: wa1/wa2/w3[r] = W[r,:] . {a1,a2,a3} (one W pass) ----------------
__global__ void prep_w_kernel(const float* __restrict__ W, const float* __restrict__ a,
                              float* __restrict__ wa1, float* __restrict__ wa2,
                              float* __restrict__ w3) {
    int lane = threadIdx.x & 63, wave = threadIdx.x >> 6;
    float4 a1v = *(const float4*)&a[lane * 4];
    float4 a2v = *(const float4*)&a[OUTF + lane * 4];
    float4 a3v = *(const float4*)&a[2 * OUTF + lane * 4];
    int r0 = blockIdx.x * 8 + wave * 2;
    #pragma unroll
    for (int rr = 0; rr < 2; ++rr) {
        int r = r0 + rr;
        float4 wv = *(const float4*)&W[(size_t)r * OUTF + lane * 4];
        float d1 = wv.x * a1v.x + wv.y * a1v.y + wv.z * a1v.z + wv.w * a1v.w;
        float d2 = wv.x * a2v.x + wv.y * a2v.y + wv.z * a2v.z + wv.w * a2v.w;
        float d3 = wv.x * a3v.x + wv.y * a3v.y + wv.z * a3v.z + wv.w * a3v.w;
        #pragma unroll
        for (int off = 32; off; off >>= 1) {
            d1 += __shfl_xor(d1, off);
            d2 += __shfl_xor(d2, off);
            d3 += __shfl_xor(d3, off);
        }
        if (lane == 0) { wa1[r] = d1; wa2[r] = d2; w3[r] = d3; }
    }
}

// ---------------- prep2 (blocks 0-15): we3 = W_e @ w3 ; sv2 (16-527): s_src/s_dst -------
__global__ void prep2_sv2_kernel(const float* __restrict__ W_e, const float* __restrict__ w3,
                                 const float* __restrict__ input,
                                 const float* __restrict__ wa1, const float* __restrict__ wa2,
                                 float* __restrict__ we3,
                                 float* __restrict__ s_src, float* __restrict__ s_dst) {
    int b = blockIdx.x, t = threadIdx.x;
    int lane = t & 63, wave = t >> 6;
    if (b < 16) {
        int r = b * 4 + wave;
        float4 wv = *(const float4*)&W_e[(size_t)r * INF_ + lane * 4];
        float4 xv = *(const float4*)&w3[lane * 4];
        float d = wv.x * xv.x + wv.y * xv.y + wv.z * xv.z + wv.w * xv.w;
        #pragma unroll
        for (int off = 32; off; off >>= 1) d += __shfl_xor(d, off);
        if (lane == 0) we3[r] = d;
    } else {
        // s_src[i] = input[i,:].wa1 ; s_dst[i] = input[i,:].wa2  (== (input@W)@a1/a2)
        int i = (b - 16) * 4 + wave;
        float acc1 = 0.f, acc2 = 0.f;
        #pragma unroll
        for (int u = 0; u < 4; ++u) {
            int o = lane + u * 64;
            float iv = input[(size_t)i * INF_ + o];
            acc1 += iv * wa1[o];
            acc2 += iv * wa2[o];
        }
        #pragma unroll
        for (int off = 32; off; off >>= 1) {
            acc1 += __shfl_xor(acc1, off);
            acc2 += __shfl_xor(acc2, off);
        }
        if (lane == 0) { s_src[i] = acc1; s_dst[i] = acc2; }
    }
}

// ---------------- mega: blocks 0-255 = h-GEMM->hbT(bf16,T); 256-2303 = score ----------------
struct ScSmem {
    float p[NN];
    float sdst[NN];
    unsigned char amask[NN];
    float swe3[EF];
    float redm[4], reds[4];
};
struct GmSmem {
    float As[64][68];
    float Bs[64][32];
};
union MegaSmem { ScSmem sc; GmSmem gm; };

__launch_bounds__(256, 6)
__global__ void mega_kernel(const float* __restrict__ input, const float* __restrict__ W,
                            const float* __restrict__ e_feat, const int* __restrict__ adj,
                            const float* __restrict__ s_src, const float* __restrict__ s_dst,
                            const float* __restrict__ we3,
                            ushortT* __restrict__ hbT, ushortT* __restrict__ attb,
                            float* __restrict__ invs) {
    __shared__ MegaSmem smem;
    int b   = blockIdx.x;
    int tid = threadIdx.x;
    int lane = tid & 63;
    int wave = tid >> 6;

    if (b < 256) {
        // ======== gemm role: 64x32 f32 tile of input@W -> transposed bf16 hbT ========
        int r0 = (b >> 3) * 64;
        int c0 = (b & 7) * 32;
        int tr = tid >> 4;
        int tc = tid & 15;
        float acc[4][2] = {};

        for (int k0 = 0; k0 < INF_; k0 += 64) {
            #pragma unroll
            for (int t = 0; t < 4; ++t) {
                int s = tid + t * 256;
                int row = s >> 4, col4 = s & 15;
                *(float4*)&smem.gm.As[row][col4 * 4] =
                    *(const float4*)&input[(size_t)(r0 + row) * INF_ + k0 + col4 * 4];
            }
            #pragma unroll
            for (int t = 0; t < 2; ++t) {
                int s = tid + t * 256;
                int row = s >> 3, col4 = s & 7;
                *(float4*)&smem.gm.Bs[row][col4 * 4] =
                    *(const float4*)&W[(size_t)(k0 + row) * 256 + c0 + col4 * 4];
            }
            __syncthreads();
            #pragma unroll
            for (int kk = 0; kk < 64; kk += 4) {
                float4 aReg[4];
                float2 bReg[4];
                #pragma unroll
                for (int i = 0; i < 4; ++i) aReg[i] = *(const float4*)&smem.gm.As[tr * 4 + i][kk];
                #pragma unroll
                for (int q = 0; q < 4; ++q)  bReg[q] = *(const float2*)&smem.gm.Bs[kk + q][tc * 2];
                #pragma unroll
                for (int q = 0; q < 4; ++q) {
                    float bx = bReg[q].x, by = bReg[q].y;
                    #pragma unroll
                    for (int i = 0; i < 4; ++i) {
                        float av = (q == 0) ? aReg[i].x : (q == 1) ? aReg[i].y
                                 : (q == 2) ? aReg[i].z : aReg[i].w;
                        acc[i][0] += av * bx;
                        acc[i][1] += av * by;
                    }
                }
            }
            __syncthreads();
        }
        // transpose epilogue: reuse Bs as tb[32 cols][72]
        ushortT (*tb)[72] = (ushortT (*)[72])smem.gm.Bs;
        #pragma unroll
        for (int i = 0; i < 4; ++i) {
            int row = tr * 4 + i;
            tb[tc * 2 + 0][row] = f2b(acc[i][0]);
            tb[tc * 2 + 1][row] = f2b(acc[i][1]);
        }
        __syncthreads();
        int n = tid >> 3, seg = tid & 7;     // 32 cols x 8 segs of 8 ushorts
        *(u16x8*)&hbT[(size_t)(c0 + n) * NN + r0 + seg * 8] =
            *(const u16x8*)&tb[n][seg * 8];
        return;
    }

    // ======== score role (R13-proven body) ========
    int i = b - 256;
    float* p    = smem.sc.p;
    float* sdst = smem.sc.sdst;
    unsigned char* amask = smem.sc.amask;
    float* swe3 = smem.sc.swe3;
    float* redm = smem.sc.redm;
    float* reds = smem.sc.reds;

    const int* arow = adj + (size_t)i * NN;
    #pragma unroll
    for (int t = 0; t < 2; ++t) {
        int s = tid * 2 + t;
        iv4 a4 = __builtin_nontemporal_load(&((const iv4*)arow)[s]);
        uchar4 m4;
        m4.x = a4.x != 0; m4.y = a4.y != 0; m4.z = a4.z != 0; m4.w = a4.w != 0;
        *(uchar4*)&amask[s * 4] = m4;
        ((float4*)sdst)[s] = ((const float4*)s_dst)[s];
    }
    if (tid < EF) swe3[tid] = we3[tid];
    __syncthreads();

    const int g  = lane >> 2;
    const int gl = lane & 3;
    const float4 wv0 = *(const float4*)&swe3[0  + gl * 4];
    const float4 wv1 = *(const float4*)&swe3[16 + gl * 4];
    const float4 wv2 = *(const float4*)&swe3[32 + gl * 4];
    const float4 wv3 = *(const float4*)&swe3[48 + gl * 4];
    const float* efrow = e_feat + (size_t)i * NN * EF;
    const int joff = wave * 16 + g;

    unsigned mbits = 0;
    #pragma unroll
    for (int k = 0; k < 32; ++k)
        mbits |= (unsigned)(amask[k * 64 + joff] != 0) << k;

    #pragma unroll 4
    for (int k = 0; k < 32; ++k) {
        int j = k * 64 + joff;
        bool av = (mbits >> k) & 1u;
        fv4 e0, e1, e2, e3;
        if (av) {
            const float* ep = efrow + (size_t)j * EF;
            e0 = ntload4(&ep[0  + gl * 4]);
            e1 = ntload4(&ep[16 + gl * 4]);
            e2 = ntload4(&ep[32 + gl * 4]);
            e3 = ntload4(&ep[48 + gl * 4]);
        }
        if (av) {
            float d = e0.x * wv0.x + e0.y * wv0.y + e0.z * wv0.z + e0.w * wv0.w
                    + e1.x * wv1.x + e1.y * wv1.y + e1.z * wv1.z + e1.w * wv1.w
                    + e2.x * wv2.x + e2.y * wv2.y + e2.z * wv2.z + e2.w * wv2.w
                    + e3.x * wv3.x + e3.y * wv3.y + e3.z * wv3.z + e3.w * wv3.w;
            d = dpp_add_xor1(d);
            d = dpp_add_xor2(d);
            if (gl == 0) p[j] = d;
        }
    }
    __syncthreads();

    const float ssrc = s_src[i];

    float m = NEG_INF;
    for (int j = tid; j < NN; j += 256) {
        if (amask[j]) {
            float s = ssrc + sdst[j] + p[j];
            s = (s > 0.f) ? s : ALPHA * s;
            m = fmaxf(m, s);
        }
    }
    #pragma unroll
    for (int off = 32; off; off >>= 1) m = fmaxf(m, __shfl_xor(m, off));
    if (lane == 0) redm[wave] = m;
    __syncthreads();
    m = fmaxf(fmaxf(redm[0], redm[1]), fmaxf(redm[2], redm[3]));
    const bool none = (m < -8.0e14f);

    ushortT* arowo = attb + (size_t)i * NN;
    float sum = 0.f;
    for (int j = tid * 2; j < NN; j += 512) {
        float e0, e1;
        if (amask[j]) {
            float s = ssrc + sdst[j] + p[j];
            s = (s > 0.f) ? s : ALPHA * s;
            e0 = __expf(s - m);
        } else e0 = none ? 1.0f : 0.0f;
        if (amask[j + 1]) {
            float s = ssrc + sdst[j + 1] + p[j + 1];
            s = (s > 0.f) ? s : ALPHA * s;
            e1 = __expf(s - m);
        } else e1 = none ? 1.0f : 0.0f;
        ushort2 uu; uu.x = f2b(e0); uu.y = f2b(e1);
        *(ushort2*)&arowo[j] = uu;
        sum += e0 + e1;
    }
    #pragma unroll
    for (int off = 32; off; off >>= 1) sum += __shfl_xor(sum, off);
    if (lane == 0) reds[wave] = sum;
    __syncthreads();
    if (tid == 0) invs[i] = 1.f / (reds[0] + reds[1] + reds[2] + reds[3]);
}

// ---------------- att(bf16) @ h(bf16): MFMA 16x16x32, 64x64 tile, split-K=4 ----------------
__launch_bounds__(256, 2)
__global__ void gemm2_mfma_kernel(const ushortT* __restrict__ attb,
                                  const ushortT* __restrict__ hbT,
                                  float* __restrict__ Cpart) {
    __shared__ ushortT As[64][72];       // [m][k], +8 pad
    __shared__ ushortT Bs[64][72];       // [n][k]
    int tid = threadIdx.x;
    int lane = tid & 63;
    int w = tid >> 6;
    int r0 = blockIdx.x * 64;
    int c0 = blockIdx.y * 64;
    int z  = blockIdx.z;
    int m = lane & 15, q = lane >> 4;
    const int srow = tid >> 2, sseg = tid & 3;

    f32x4 acc0 = {0.f, 0.f, 0.f, 0.f};
    f32x4 acc1 = {0.f, 0.f, 0.f, 0.f};
    f32x4 acc2 = {0.f, 0.f, 0.f, 0.f};
    f32x4 acc3 = {0.f, 0.f, 0.f, 0.f};

    for (int k0 = z * (NN / 4); k0 < (z + 1) * (NN / 4); k0 += 64) {
        {
            const size_t abase = (size_t)(r0 + srow) * NN + k0 + sseg * 16;
            *(u16x8*)&As[srow][sseg * 16]     = *(const u16x8*)&attb[abase];
            *(u16x8*)&As[srow][sseg * 16 + 8] = *(const u16x8*)&attb[abase + 8];
            const size_t bbase = (size_t)(c0 + srow) * NN + k0 + sseg * 16;
            *(u16x8*)&Bs[srow][sseg * 16]     = *(const u16x8*)&hbT[bbase];
            *(u16x8*)&Bs[srow][sseg * 16 + 8] = *(const u16x8*)&hbT[bbase + 8];
        }
        __syncthreads();
        #pragma unroll
        for (int kk = 0; kk < 2; ++kk) {
            short4v a0 = *(const short4v*)&As[w * 16 + m][kk * 32 + q * 4];
            short4v a1 = *(const short4v*)&As[w * 16 + m][kk * 32 + 16 + q * 4];
            short8v af = {a0.x, a0.y, a0.z, a0.w, a1.x, a1.y, a1.z, a1.w};
            #pragma unroll
            for (int nb = 0; nb < 4; ++nb) {
                short4v b0 = *(const short4v*)&Bs[nb * 16 + m][kk * 32 + q * 4];
                short4v b1 = *(const short4v*)&Bs[nb * 16 + m][kk * 32 + 16 + q * 4];
                short8v bf = {b0.x, b0.y, b0.z, b0.w, b1.x, b1.y, b1.z, b1.w};
                if (nb == 0) acc0 = __builtin_amdgcn_mfma_f32_16x16x32_bf16(af, bf, acc0, 0, 0, 0);
                if (nb == 1) acc1 = __builtin_amdgcn_mfma_f32_16x16x32_bf16(af, bf, acc1, 0, 0, 0);
                if (nb == 2) acc2 = __builtin_amdgcn_mfma_f32_16x16x32_bf16(af, bf, acc2, 0, 0, 0);
                if (nb == 3) acc3 = __builtin_amdgcn_mfma_f32_16x16x32_bf16(af, bf, acc3, 0, 0, 0);
            }
        }
        __syncthreads();
    }
    float* Cz = Cpart + (size_t)z * NN * OUTF;
    #pragma unroll
    for (int r = 0; r < 4; ++r) {
        int row = r0 + w * 16 + q * 4 + r;
        Cz[(size_t)row * OUTF + c0 + 0  + m] = acc0[r];
        Cz[(size_t)row * OUTF + c0 + 16 + m] = acc1[r];
        Cz[(size_t)row * OUTF + c0 + 32 + m] = acc2[r];
        Cz[(size_t)row * OUTF + c0 + 48 + m] = acc3[r];
    }
}

// ---------------- combine 4 partials + normalize + ELU ----------------
__global__ void combine_kernel(const float* __restrict__ Cpart, const float* __restrict__ invs,
                               float* __restrict__ out) {
    int i = blockIdx.x, t = threadIdx.x;
    size_t idx = (size_t)i * OUTF + t;
    const size_t P = (size_t)NN * OUTF;
    float v = (Cpart[idx] + Cpart[P + idx] + Cpart[2 * P + idx] + Cpart[3 * P + idx]) * invs[i];
    out[idx] = v > 0.f ? v : __expf(v) - 1.f;
}

extern "C" void kernel_launch(void* const* d_in, const int* in_sizes, int n_in,
                              void* d_out, int out_size, void* d_ws, size_t ws_size,
                              hipStream_t stream) {
    const float* input  = (const float*)d_in[0];
    const int*   adj    = (const int*)  d_in[1];
    const float* e_feat = (const float*)d_in[2];
    const float* W_e    = (const float*)d_in[3];
    const float* W      = (const float*)d_in[4];
    const float* a      = (const float*)d_in[5];
    float* out = (float*)d_out;

    float*   ws    = (float*)d_ws;
    float*   wa1   = ws;                          // 256
    float*   wa2   = wa1 + INF_;                  // 256
    float*   w3    = wa2 + INF_;                  // 256
    float*   we3   = w3 + INF_;                   // 64
    float*   s_src = we3 + EF;                    // 2048
    float*   s_dst = s_src + NN;                  // 2048
    float*   invs  = s_dst + NN;                  // 2048
    ushortT* attb  = (ushortT*)(invs + NN);       // 2048*2048 bf16 (8.4 MB)
    ushortT* hbT   = attb + (size_t)NN * NN;      // 256*2048 bf16 (1 MB)
    float*   cpart = (float*)(hbT + (size_t)OUTF * NN);  // 4 * 2048*256 f32 (8.4 MB)

    prep_w_kernel<<<32, 256, 0, stream>>>(W, a, wa1, wa2, w3);
    prep2_sv2_kernel<<<16 + NN / 4, 256, 0, stream>>>(W_e, w3, input, wa1, wa2,
                                                      we3, s_src, s_dst);
    mega_kernel<<<256 + NN, 256, 0, stream>>>(input, W, e_feat, adj, s_src, s_dst, we3,
                                              hbT, attb, invs);
    gemm2_mfma_kernel<<<dim3(NN / 64, OUTF / 64, 4), 256, 0, stream>>>(attb, hbT, cpart);
    combine_kernel<<<NN, 256, 0, stream>>>(cpart, invs, out);
}

// Round 15
// 141.536 us; speedup vs baseline: 1.3036x; 1.3036x over previous
//
#include <hip/hip_runtime.h>
#include <math.h>

#define NN   2048
#define INF_ 256
#define OUTF 256
#define EF   64
#define ALPHA 0.2f
#define NEG_INF -9000000000000000.0f

typedef unsigned short ushortT;
typedef __attribute__((ext_vector_type(8))) short    short8v;
typedef __attribute__((ext_vector_type(4))) short    short4v;
typedef __attribute__((ext_vector_type(8))) unsigned short u16x8;
typedef __attribute__((ext_vector_type(4))) float    f32x4;
typedef __attribute__((ext_vector_type(4))) float    fv4;   // clang vector: NT-load legal
typedef __attribute__((ext_vector_type(4))) int      iv4;

__device__ __forceinline__ ushortT f2b(float f) {      // RNE; inputs are finite
    unsigned b = *(unsigned*)&f;
    unsigned r = (b + 0x7FFFu + ((b >> 16) & 1u)) >> 16;
    return (ushortT)r;
}
// quad_perm DPP lane-xor add (VALU pipe, no LDS)
__device__ __forceinline__ float dpp_add_xor1(float x) {
    int xi = *(int*)&x;
    int r = __builtin_amdgcn_mov_dpp(xi, 0xB1, 0xF, 0xF, true);  // [1,0,3,2]
    float rf = *(float*)&r;
    return x + rf;
}
__device__ __forceinline__ float dpp_add_xor2(float x) {
    int xi = *(int*)&x;
    int r = __builtin_amdgcn_mov_dpp(xi, 0x4E, 0xF, 0xF, true);  // [2,3,0,1]
    float rf = *(float*)&r;
    return x + rf;
}
__device__ __forceinline__ fv4 ntload4(const float* p) {
    return __builtin_nontemporal_load((const fv4*)p);
}

// ---------------- prep1: w3[r] = W[r,:] . a3 ----------------
__global__ void prep1_kernel(const float* __restrict__ W, const float* __restrict__ a,
                             float* __restrict__ w3) {
    int lane = threadIdx.x & 63, wave = threadIdx.x >> 6;
    const float* a3 = a + 2 * OUTF;
    float4 av = *(const float4*)&a3[lane * 4];
    int r0 = blockIdx.x * 8 + wave * 2;
    #pragma unroll
    for (int rr = 0; rr < 2; ++rr) {
        int r = r0 + rr;
        float4 wv = *(const float4*)&W[(size_t)r * OUTF + lane * 4];
        float d = wv.x * av.x + wv.y * av.y + wv.z * av.z + wv.w * av.w;
        #pragma unroll
        for (int off = 32; off; off >>= 1) d += __shfl_xor(d, off);
        if (lane == 0) w3[r] = d;
    }
}

// ---------------- prep2: we3[r] = W_e[r,:] . w3 ----------------
__global__ void prep2_kernel(const float* __restrict__ W_e, const float* __restrict__ w3,
                             float* __restrict__ we3) {
    int lane = threadIdx.x & 63, wave = threadIdx.x >> 6;
    int r = blockIdx.x * 4 + wave;
    float4 wv = *(const float4*)&W_e[(size_t)r * INF_ + lane * 4];
    float4 xv = *(const float4*)&w3[lane * 4];
    float d = wv.x * xv.x + wv.y * xv.y + wv.z * xv.z + wv.w * xv.w;
    #pragma unroll
    for (int off = 32; off; off >>= 1) d += __shfl_xor(d, off);
    if (lane == 0) we3[r] = d;
}

// ---------------- h = input @ W: 64x32 tile f32 ----------------
template<int K>
__launch_bounds__(256, 2)
__global__ void gemm_kernel(const float* __restrict__ A, const float* __restrict__ Bm,
                            float* __restrict__ C) {
    __shared__ float As[64][68];
    __shared__ float Bs[64][32];
    int tid = threadIdx.x;
    int r0 = blockIdx.x * 64;
    int c0 = blockIdx.y * 32;
    int tr = tid >> 4;
    int tc = tid & 15;
    float acc[4][2] = {};

    for (int k0 = 0; k0 < K; k0 += 64) {
        #pragma unroll
        for (int t = 0; t < 4; ++t) {
            int s = tid + t * 256;
            int row = s >> 4, col4 = s & 15;
            *(float4*)&As[row][col4 * 4] =
                *(const float4*)&A[(size_t)(r0 + row) * K + k0 + col4 * 4];
        }
        #pragma unroll
        for (int t = 0; t < 2; ++t) {
            int s = tid + t * 256;
            int row = s >> 3, col4 = s & 7;
            *(float4*)&Bs[row][col4 * 4] =
                *(const float4*)&Bm[(size_t)(k0 + row) * 256 + c0 + col4 * 4];
        }
        __syncthreads();
        #pragma unroll
        for (int kk = 0; kk < 64; kk += 4) {
            float4 aReg[4];
            float2 bReg[4];
            #pragma unroll
            for (int i = 0; i < 4; ++i) aReg[i] = *(const float4*)&As[tr * 4 + i][kk];
            #pragma unroll
            for (int q = 0; q < 4; ++q)  bReg[q] = *(const float2*)&Bs[kk + q][tc * 2];
            #pragma unroll
            for (int q = 0; q < 4; ++q) {
                float bx = bReg[q].x, by = bReg[q].y;
                #pragma unroll
                for (int i = 0; i < 4; ++i) {
                    float av = (q == 0) ? aReg[i].x : (q == 1) ? aReg[i].y
                             : (q == 2) ? aReg[i].z : aReg[i].w;
                    acc[i][0] += av * bx;
                    acc[i][1] += av * by;
                }
            }
        }
        __syncthreads();
    }
    #pragma unroll
    for (int i = 0; i < 4; ++i) {
        int r = r0 + tr * 4 + i;
        float2 v = {acc[i][0], acc[i][1]};
        *(float2*)&C[(size_t)r * 256 + c0 + tc * 2] = v;
    }
}

// ---------------- merged: xpose (blocks 0-127) + sv (blocks 128-639) ----------------
__global__ void xpose_sv_kernel(const float* __restrict__ h, const float* __restrict__ a,
                                ushortT* __restrict__ hbT,
                                float* __restrict__ s_src, float* __restrict__ s_dst) {
    __shared__ ushortT tb[64][72];       // [n][r], padded (xpose role only)
    int b = blockIdx.x;
    int t = threadIdx.x;
    if (b < 128) {
        // ---- xpose role: h (f32 [2048][256]) tile -> hbT (bf16 [256][2048]) ----
        int r0 = (b >> 2) * 64;          // h-row tile
        int n0 = (b & 3) * 64;           // h-col tile
        int row = t >> 2, seg = t & 3;   // 16 cols per thread
        #pragma unroll
        for (int c = 0; c < 4; ++c) {
            float4 v = *(const float4*)&h[(size_t)(r0 + row) * OUTF + n0 + seg * 16 + c * 4];
            tb[seg * 16 + c * 4 + 0][row] = f2b(v.x);
            tb[seg * 16 + c * 4 + 1][row] = f2b(v.y);
            tb[seg * 16 + c * 4 + 2][row] = f2b(v.z);
            tb[seg * 16 + c * 4 + 3][row] = f2b(v.w);
        }
        __syncthreads();
        *(u16x8*)&hbT[(size_t)(n0 + row) * NN + r0 + seg * 16] =
            *(const u16x8*)&tb[row][seg * 16];
        *(u16x8*)&hbT[(size_t)(n0 + row) * NN + r0 + seg * 16 + 8] =
            *(const u16x8*)&tb[row][seg * 16 + 8];
    } else {
        // ---- sv role: s_src = h@a1, s_dst = h@a2 ----
        int lane = t & 63;
        int wave = t >> 6;
        int i = (b - 128) * 4 + wave;
        float acc1 = 0.f, acc2 = 0.f;
        #pragma unroll
        for (int u = 0; u < 4; ++u) {
            int o = lane + u * 64;
            float hv = h[(size_t)i * OUTF + o];
            acc1 += hv * a[o];
            acc2 += hv * a[OUTF + o];
        }
        #pragma unroll
        for (int off = 32; off; off >>= 1) {
            acc1 += __shfl_xor(acc1, off);
            acc2 += __shfl_xor(acc2, off);
        }
        if (lane == 0) { s_src[i] = acc1; s_dst[i] = acc2; }
    }
}

// ---------------- att(bf16) @ h(bf16): MFMA 16x16x32, 64x64 tile, split-K=4 ----------------
__launch_bounds__(256, 2)
__global__ void gemm2_mfma_kernel(const ushortT* __restrict__ attb,
                                  const ushortT* __restrict__ hbT,
                                  float* __restrict__ Cpart) {
    __shared__ ushortT As[64][72];       // [m][k], +8 pad
    __shared__ ushortT Bs[64][72];       // [n][k]
    int tid = threadIdx.x;
    int lane = tid & 63;
    int w = tid >> 6;
    int r0 = blockIdx.x * 64;
    int c0 = blockIdx.y * 64;
    int z  = blockIdx.z;
    int m = lane & 15, q = lane >> 4;
    const int srow = tid >> 2, sseg = tid & 3;

    f32x4 acc0 = {0.f, 0.f, 0.f, 0.f};
    f32x4 acc1 = {0.f, 0.f, 0.f, 0.f};
    f32x4 acc2 = {0.f, 0.f, 0.f, 0.f};
    f32x4 acc3 = {0.f, 0.f, 0.f, 0.f};

    for (int k0 = z * (NN / 4); k0 < (z + 1) * (NN / 4); k0 += 64) {
        {
            const size_t abase = (size_t)(r0 + srow) * NN + k0 + sseg * 16;
            *(u16x8*)&As[srow][sseg * 16]     = *(const u16x8*)&attb[abase];
            *(u16x8*)&As[srow][sseg * 16 + 8] = *(const u16x8*)&attb[abase + 8];
            const size_t bbase = (size_t)(c0 + srow) * NN + k0 + sseg * 16;
            *(u16x8*)&Bs[srow][sseg * 16]     = *(const u16x8*)&hbT[bbase];
            *(u16x8*)&Bs[srow][sseg * 16 + 8] = *(const u16x8*)&hbT[bbase + 8];
        }
        __syncthreads();
        #pragma unroll
        for (int kk = 0; kk < 2; ++kk) {
            short4v a0 = *(const short4v*)&As[w * 16 + m][kk * 32 + q * 4];
            short4v a1 = *(const short4v*)&As[w * 16 + m][kk * 32 + 16 + q * 4];
            short8v af = {a0.x, a0.y, a0.z, a0.w, a1.x, a1.y, a1.z, a1.w};
            #pragma unroll
            for (int nb = 0; nb < 4; ++nb) {
                short4v b0 = *(const short4v*)&Bs[nb * 16 + m][kk * 32 + q * 4];
                short4v b1 = *(const short4v*)&Bs[nb * 16 + m][kk * 32 + 16 + q * 4];
                short8v bf = {b0.x, b0.y, b0.z, b0.w, b1.x, b1.y, b1.z, b1.w};
                if (nb == 0) acc0 = __builtin_amdgcn_mfma_f32_16x16x32_bf16(af, bf, acc0, 0, 0, 0);
                if (nb == 1) acc1 = __builtin_amdgcn_mfma_f32_16x16x32_bf16(af, bf, acc1, 0, 0, 0);
                if (nb == 2) acc2 = __builtin_amdgcn_mfma_f32_16x16x32_bf16(af, bf, acc2, 0, 0, 0);
                if (nb == 3) acc3 = __builtin_amdgcn_mfma_f32_16x16x32_bf16(af, bf, acc3, 0, 0, 0);
            }
        }
        __syncthreads();
    }
    float* Cz = Cpart + (size_t)z * NN * OUTF;
    #pragma unroll
    for (int r = 0; r < 4; ++r) {
        int row = r0 + w * 16 + q * 4 + r;
        Cz[(size_t)row * OUTF + c0 + 0  + m] = acc0[r];
        Cz[(size_t)row * OUTF + c0 + 16 + m] = acc1[r];
        Cz[(size_t)row * OUTF + c0 + 32 + m] = acc2[r];
        Cz[(size_t)row * OUTF + c0 + 48 + m] = acc3[r];
    }
}

// ---------------- combine 4 partials + normalize + ELU ----------------
__global__ void combine_kernel(const float* __restrict__ Cpart, const float* __restrict__ invs,
                               float* __restrict__ out) {
    int i = blockIdx.x, t = threadIdx.x;
    size_t idx = (size_t)i * OUTF + t;
    const size_t P = (size_t)NN * OUTF;
    float v = (Cpart[idx] + Cpart[P + idx] + Cpart[2 * P + idx] + Cpart[3 * P + idx]) * invs[i];
    out[idx] = v > 0.f ? v : __expf(v) - 1.f;
}

// ---------------- scores + softmax: mask-upfront, DPP reduce, NT streaming loads -------
__launch_bounds__(256, 6)
__global__ void score_kernel(const float* __restrict__ e_feat, const int* __restrict__ adj,
                             const float* __restrict__ s_src, const float* __restrict__ s_dst,
                             const float* __restrict__ we3,
                             ushortT* __restrict__ attb, float* __restrict__ invs) {
    __shared__ float p[NN];              // 8 KiB: raw dot values (enabled cols only)
    __shared__ float sdst[NN];           // 8 KiB
    __shared__ unsigned char amask[NN];  // 2 KiB
    __shared__ float swe3[EF];
    __shared__ float redm[4], reds[4];

    int tid  = threadIdx.x;
    int lane = tid & 63;
    int wave = tid >> 6;
    int i    = blockIdx.x;

    const int* arow = adj + (size_t)i * NN;
    #pragma unroll
    for (int t = 0; t < 2; ++t) {
        int s = tid * 2 + t;
        iv4 a4 = __builtin_nontemporal_load(&((const iv4*)arow)[s]);
        uchar4 m4;
        m4.x = a4.x != 0; m4.y = a4.y != 0; m4.z = a4.z != 0; m4.w = a4.w != 0;
        *(uchar4*)&amask[s * 4] = m4;
        ((float4*)sdst)[s] = ((const float4*)s_dst)[s];
    }
    if (tid < EF) swe3[tid] = we3[tid];
    __syncthreads();

    const int g  = lane >> 2;
    const int gl = lane & 3;
    const float4 wv0 = *(const float4*)&swe3[0  + gl * 4];
    const float4 wv1 = *(const float4*)&swe3[16 + gl * 4];
    const float4 wv2 = *(const float4*)&swe3[32 + gl * 4];
    const float4 wv3 = *(const float4*)&swe3[48 + gl * 4];
    const float* efrow = e_feat + (size_t)i * NN * EF;
    const int joff = wave * 16 + g;

    unsigned mbits = 0;
    #pragma unroll
    for (int k = 0; k < 32; ++k)
        mbits |= (unsigned)(amask[k * 64 + joff] != 0) << k;

    #pragma unroll 4
    for (int k = 0; k < 32; ++k) {
        int j = k * 64 + joff;
        bool av = (mbits >> k) & 1u;
        fv4 e0, e1, e2, e3;
        if (av) {
            const float* ep = efrow + (size_t)j * EF;
            e0 = ntload4(&ep[0  + gl * 4]);
            e1 = ntload4(&ep[16 + gl * 4]);
            e2 = ntload4(&ep[32 + gl * 4]);
            e3 = ntload4(&ep[48 + gl * 4]);
        }
        if (av) {
            float d = e0.x * wv0.x + e0.y * wv0.y + e0.z * wv0.z + e0.w * wv0.w
                    + e1.x * wv1.x + e1.y * wv1.y + e1.z * wv1.z + e1.w * wv1.w
                    + e2.x * wv2.x + e2.y * wv2.y + e2.z * wv2.z + e2.w * wv2.w
                    + e3.x * wv3.x + e3.y * wv3.y + e3.z * wv3.z + e3.w * wv3.w;
            d = dpp_add_xor1(d);
            d = dpp_add_xor2(d);
            if (gl == 0) p[j] = d;
        }
    }
    __syncthreads();

    const float ssrc = s_src[i];

    float m = NEG_INF;
    for (int j = tid; j < NN; j += 256) {
        if (amask[j]) {
            float s = ssrc + sdst[j] + p[j];
            s = (s > 0.f) ? s : ALPHA * s;
            m = fmaxf(m, s);
        }
    }
    #pragma unroll
    for (int off = 32; off; off >>= 1) m = fmaxf(m, __shfl_xor(m, off));
    if (lane == 0) redm[wave] = m;
    __syncthreads();
    m = fmaxf(fmaxf(redm[0], redm[1]), fmaxf(redm[2], redm[3]));
    const bool none = (m < -8.0e14f);

    ushortT* arowo = attb + (size_t)i * NN;
    float sum = 0.f;
    for (int j = tid * 2; j < NN; j += 512) {
        float e0, e1;
        if (amask[j]) {
            float s = ssrc + sdst[j] + p[j];
            s = (s > 0.f) ? s : ALPHA * s;
            e0 = __expf(s - m);
        } else e0 = none ? 1.0f : 0.0f;
        if (amask[j + 1]) {
            float s = ssrc + sdst[j + 1] + p[j + 1];
            s = (s > 0.f) ? s : ALPHA * s;
            e1 = __expf(s - m);
        } else e1 = none ? 1.0f : 0.0f;
        ushort2 uu; uu.x = f2b(e0); uu.y = f2b(e1);
        *(ushort2*)&arowo[j] = uu;
        sum += e0 + e1;
    }
    #pragma unroll
    for (int off = 32; off; off >>= 1) sum += __shfl_xor(sum, off);
    if (lane == 0) reds[wave] = sum;
    __syncthreads();
    if (tid == 0) invs[i] = 1.f / (reds[0] + reds[1] + reds[2] + reds[3]);
}

extern "C" void kernel_launch(void* const* d_in, const int* in_sizes, int n_in,
                              void* d_out, int out_size, void* d_ws, size_t ws_size,
                              hipStream_t stream) {
    const float* input  = (const float*)d_in[0];
    const int*   adj    = (const int*)  d_in[1];
    const float* e_feat = (const float*)d_in[2];
    const float* W_e    = (const float*)d_in[3];
    const float* W      = (const float*)d_in[4];
    const float* a      = (const float*)d_in[5];
    float* out = (float*)d_out;

    float*   ws    = (float*)d_ws;
    float*   h     = ws;                          // 2048*256 f32 (2 MB)
    float*   s_src = h + (size_t)NN * OUTF;       // 2048
    float*   s_dst = s_src + NN;                  // 2048
    float*   w3    = s_dst + NN;                  // 256
    float*   we3   = w3 + INF_;                   // 64
    float*   invs  = we3 + EF;                    // 2048
    ushortT* attb  = (ushortT*)(invs + NN);       // 2048*2048 bf16 (8.4 MB)
    ushortT* hbT   = attb + (size_t)NN * NN;      // 256*2048 bf16 (1 MB)
    float*   cpart = (float*)(hbT + (size_t)OUTF * NN);  // 4 * 2048*256 f32 (8.4 MB)

    prep1_kernel<<<32, 256, 0, stream>>>(W, a, w3);
    prep2_kernel<<<16, 256, 0, stream>>>(W_e, w3, we3);
    gemm_kernel<INF_><<<dim3(NN / 64, 8), 256, 0, stream>>>(input, W, h);
    xpose_sv_kernel<<<128 + NN / 4, 256, 0, stream>>>(h, a, hbT, s_src, s_dst);
    score_kernel<<<NN, 256, 0, stream>>>(e_feat, adj, s_src, s_dst, we3, attb, invs);
    gemm2_mfma_kernel<<<dim3(NN / 64, OUTF / 64, 4), 256, 0, stream>>>(attb, hbT, cpart);
    combine_kernel<<<NN, 256, 0, stream>>>(cpart, invs, out);
}